// Round 1
// 731.999 us; speedup vs baseline: 1.0380x; 1.0380x over previous
//
#include <hip/hip_runtime.h>
#include <stdint.h>

#define DIN 4096
#define DOUT 4096
#define RNK 8
#define MROWS 8192   // B*S = 4*2048

typedef unsigned short u16;
typedef __attribute__((ext_vector_type(8))) short short8;
typedef __attribute__((ext_vector_type(8))) unsigned short u16x8;
typedef __attribute__((ext_vector_type(4))) float f32x4;

// ---------- helpers ----------
__device__ __forceinline__ u16 f2bf(float f) {
    union { float f; uint32_t u; } v; v.f = f;
    uint32_t u = v.u;
    uint32_t r = (u + 0x7fffu + ((u >> 16) & 1u)) >> 16;   // RNE
    return (u16)r;
}

__device__ __forceinline__ void gl_lds16(const u16* g, u16* lds) {
    // direct global->LDS DMA, 16B per lane; LDS dest = wave-uniform base + lane*16
    __builtin_amdgcn_global_load_lds((const __attribute__((address_space(1))) unsigned int*)g,
                                     (__attribute__((address_space(3))) unsigned int*)lds,
                                     16, 0, 0);
}

// ---------- K1: normalize columns of hra_u -> Un[i][d] (column-major by i) ----------
__global__ __launch_bounds__(256) void k_normalize_u(const float* __restrict__ hra_u,
                                                     float* __restrict__ Un) {
    const int i = blockIdx.x;        // column 0..7
    const int t = threadIdx.x;
    float ss = 0.f;
    for (int d = t; d < DIN; d += 256) {
        float v = hra_u[d * RNK + i];
        ss += v * v;
    }
    for (int off = 32; off; off >>= 1) ss += __shfl_down(ss, off, 64);
    __shared__ float red[4];
    if ((t & 63) == 0) red[t >> 6] = ss;
    __syncthreads();
    float inv = rsqrtf(red[0] + red[1] + red[2] + red[3]);
    for (int d = t; d < DIN; d += 256)
        Un[i * DIN + d] = hra_u[d * RNK + i] * inv;
}

// ---------- K2: Gram matrix G[i][j] = Un[i] . Un[j] ----------
__global__ __launch_bounds__(256) void k_gram(const float* __restrict__ Un,
                                              float* __restrict__ G) {
    const int t = threadIdx.x;
    float acc[RNK][RNK] = {};
    for (int d = t; d < DIN; d += 256) {
        float u[RNK];
        #pragma unroll
        for (int i = 0; i < RNK; i++) u[i] = Un[i * DIN + d];
        #pragma unroll
        for (int i = 0; i < RNK; i++)
            #pragma unroll
            for (int j = 0; j < RNK; j++)
                acc[i][j] += u[i] * u[j];
    }
    #pragma unroll
    for (int i = 0; i < RNK; i++)
        #pragma unroll
        for (int j = 0; j < RNK; j++)
            for (int off = 32; off; off >>= 1)
                acc[i][j] += __shfl_down(acc[i][j], off, 64);
    __shared__ float red[4][64];
    if ((t & 63) == 0) {
        #pragma unroll
        for (int i = 0; i < RNK; i++)
            #pragma unroll
            for (int j = 0; j < RNK; j++)
                red[t >> 6][i * RNK + j] = acc[i][j];
    }
    __syncthreads();
    if (t < 64) G[t] = red[0][t] + red[1][t] + red[2][t] + red[3][t];
}

// ---------- K3: per row o: v = W[o,:] @ Un^T, then y_i = 2(v_i - sum_{j<i} y_j G[j,i]) ----------
__global__ __launch_bounds__(256) void k_wy(const float* __restrict__ W,
                                            const float* __restrict__ Un,
                                            const float* __restrict__ G,
                                            float* __restrict__ Y) {
    const int o = blockIdx.x;
    const int t = threadIdx.x;
    const float* wrow = W + (size_t)o * DIN;
    float acc[RNK] = {};
    for (int d = t; d < DIN; d += 256) {
        float wv = wrow[d];
        #pragma unroll
        for (int i = 0; i < RNK; i++) acc[i] += wv * Un[i * DIN + d];
    }
    #pragma unroll
    for (int i = 0; i < RNK; i++)
        for (int off = 32; off; off >>= 1)
            acc[i] += __shfl_down(acc[i], off, 64);
    __shared__ float red[4][RNK];
    if ((t & 63) == 0) {
        #pragma unroll
        for (int i = 0; i < RNK; i++) red[t >> 6][i] = acc[i];
    }
    __syncthreads();
    if (t == 0) {
        float y[RNK];
        #pragma unroll
        for (int i = 0; i < RNK; i++) {
            float s = red[0][i] + red[1][i] + red[2][i] + red[3][i];
            for (int j = 0; j < i; j++) s -= y[j] * G[j * RNK + i];
            y[i] = 2.f * s;
            Y[(size_t)o * RNK + i] = y[i];
        }
    }
}

// ---------- K4: W'[o][d] = W[o][d] - sum_i Y[o][i]*Un[i][d], cast to bf16 ----------
__global__ __launch_bounds__(256) void k_build_w(const float* __restrict__ W,
                                                 const float* __restrict__ Un,
                                                 const float* __restrict__ Y,
                                                 u16* __restrict__ Wb) {
    const int c = blockIdx.x * 256 + threadIdx.x;  // float4 chunk id
    const int o = c >> 10;                         // row (1024 chunks per row)
    const int d = (c & 1023) * 4;
    float y[RNK];
    #pragma unroll
    for (int i = 0; i < RNK; i++) y[i] = Y[(size_t)o * RNK + i];
    float4 r = *(const float4*)(W + (size_t)o * DIN + d);
    #pragma unroll
    for (int i = 0; i < RNK; i++) {
        float4 uv = *(const float4*)(Un + i * DIN + d);
        r.x -= y[i] * uv.x; r.y -= y[i] * uv.y;
        r.z -= y[i] * uv.z; r.w -= y[i] * uv.w;
    }
    ushort4 ov;
    ov.x = f2bf(r.x); ov.y = f2bf(r.y); ov.z = f2bf(r.z); ov.w = f2bf(r.w);
    *(ushort4*)(Wb + (size_t)o * DIN + d) = ov;
}

// ---------- K5: cast x (fp32) -> bf16 ----------
__global__ __launch_bounds__(256) void k_cast_x(const float* __restrict__ x,
                                                u16* __restrict__ xb) {
    const size_t idx = (size_t)blockIdx.x * 256 + threadIdx.x;  // 8 elems each
    float4 a = *(const float4*)(x + idx * 8);
    float4 b = *(const float4*)(x + idx * 8 + 4);
    u16x8 o;
    o[0] = f2bf(a.x); o[1] = f2bf(a.y); o[2] = f2bf(a.z); o[3] = f2bf(a.w);
    o[4] = f2bf(b.x); o[5] = f2bf(b.y); o[6] = f2bf(b.z); o[7] = f2bf(b.w);
    *(u16x8*)(xb + idx * 8) = o;
}

// ---------- K6: main GEMM  C[M,N] = A[M,K] @ B[N,K]^T + bias ----------
// 128x128 tile, BK=64, 256 threads = 4 waves (2x2), each wave 64x64 via 4x4 MFMA 16x16x32.
// LDS rows are 128B (8 x 16B chunks), XOR-swizzled: logical chunk c of row r lives at
// physical chunk c^(r&7). global_load_lds writes linearly, so the swizzle is applied to
// the per-lane GLOBAL source address (a permutation within each 128B segment -> still
// fully coalesced) and to the ds_read offsets. This spreads a quad-group's 16 lanes
// across all 8 bank-quads (2 lanes/bank = free) instead of 2 (8-way conflict at BK=32).
__global__ __launch_bounds__(256) void k_gemm(const u16* __restrict__ A,   // x bf16 [M][K]
                                              const u16* __restrict__ B,   // W' bf16 [N][K]
                                              const float* __restrict__ bias,
                                              float* __restrict__ C) {
    __shared__ u16 As[128 * 64];   // 16 KiB, swizzled row-major [m][k]
    __shared__ u16 Bs[128 * 64];

    const int t = threadIdx.x;
    const int w = t >> 6, l = t & 63;

    // XCD-aware bijective swizzle (nwg = 2048, 2048 % 8 == 0): each XCD gets a
    // contiguous chunk of the tile space -> B panels stay L2-resident per XCD.
    const int nwg = gridDim.x;               // 64 * 32 = 2048
    const int cpx = nwg >> 3;                // 256 blocks per XCD
    const int bid = (blockIdx.x & 7) * cpx + (blockIdx.x >> 3);
    const int bm = bid & 63;   // M/128 = 64
    const int bn = bid >> 6;   // N/128 = 32
    const int wm = w & 1, wn = w >> 1;

    // staging: each gl_lds16 covers 8 rows x 64 k. lane l -> row (l>>3), phys chunk (l&3..7)=(l&7).
    // Row group is 8-aligned, so row&7 == l>>3; the lane must FETCH logical chunk (l&7)^(l>>3).
    const int srow = l >> 3;                    // 0..7 within 8-row group
    const int schunk = (l & 7) ^ srow;          // swizzled source chunk (16B units)
    const u16* agp = A + (size_t)(bm * 128 + w * 32 + srow) * DIN + schunk * 8;
    const u16* bgp = B + (size_t)(bn * 128 + w * 32 + srow) * DIN + schunk * 8;

    const int quad = l >> 4, lane16 = l & 15;
    const int rxor = lane16 & 7;                // row&7 for all fragment rows this lane reads

    f32x4 acc[4][4] = {};

    for (int k0 = 0; k0 < DIN; k0 += 64) {
        __syncthreads();   // previous compute done before overwrite
        #pragma unroll
        for (int j = 0; j < 4; j++) {
            gl_lds16(agp + k0 + j * 8 * DIN, &As[(w * 32 + j * 8) * 64]);
            gl_lds16(bgp + k0 + j * 8 * DIN, &Bs[(w * 32 + j * 8) * 64]);
        }
        __syncthreads();   // compiler emits vmcnt(0) drain before barrier

        #pragma unroll
        for (int kk = 0; kk < 2; kk++) {
            short8 a_frag[4], b_frag[4];
            #pragma unroll
            for (int mt = 0; mt < 4; mt++)
                a_frag[mt] = *(const short8*)
                    &As[(wm * 64 + mt * 16 + lane16) * 64 + ((kk * 4 + quad) ^ rxor) * 8];
            #pragma unroll
            for (int nt = 0; nt < 4; nt++)
                b_frag[nt] = *(const short8*)
                    &Bs[(wn * 64 + nt * 16 + lane16) * 64 + ((kk * 4 + quad) ^ rxor) * 8];
            #pragma unroll
            for (int mt = 0; mt < 4; mt++)
                #pragma unroll
                for (int nt = 0; nt < 4; nt++)
                    acc[mt][nt] = __builtin_amdgcn_mfma_f32_16x16x32_bf16(
                        a_frag[mt], b_frag[nt], acc[mt][nt], 0, 0, 0);
        }
    }

    // epilogue: D layout col=lane&15, row=quad*4+reg
    const int col0 = bn * 128 + wn * 64 + lane16;
    const int row0 = bm * 128 + wm * 64 + quad * 4;
    #pragma unroll
    for (int nt = 0; nt < 4; nt++) {
        float bv = bias[col0 + nt * 16];
        #pragma unroll
        for (int mt = 0; mt < 4; mt++) {
            #pragma unroll
            for (int rr = 0; rr < 4; rr++) {
                C[(size_t)(row0 + mt * 16 + rr) * DOUT + col0 + nt * 16] =
                    acc[mt][nt][rr] + bv;
            }
        }
    }
}

extern "C" void kernel_launch(void* const* d_in, const int* in_sizes, int n_in,
                              void* d_out, int out_size, void* d_ws, size_t ws_size,
                              hipStream_t stream) {
    const float* x     = (const float*)d_in[0];   // [4,2048,4096]
    const float* hra_u = (const float*)d_in[1];   // [4096,8]
    const float* W     = (const float*)d_in[2];   // [4096,4096]
    const float* bias  = (const float*)d_in[3];   // [4096]
    float* out = (float*)d_out;

    char* ws = (char*)d_ws;
    float* Un = (float*)(ws);                         // 8*4096*4   = 131072 B
    float* G  = (float*)(ws + 131072);                // 64*4       = 256 B
    float* Y  = (float*)(ws + 131072 + 512);          // 4096*8*4   = 131072 B
    u16*   Wb = (u16*)(ws + 524288);                  // 4096*4096*2 = 33554432 B
    u16*   xb = (u16*)(ws + 524288 + 33554432);       // 8192*4096*2 = 67108864 B

    k_normalize_u<<<RNK, 256, 0, stream>>>(hra_u, Un);
    k_gram<<<1, 256, 0, stream>>>(Un, G);
    k_wy<<<DOUT, 256, 0, stream>>>(W, Un, G, Y);
    k_build_w<<<(DOUT * DIN / 4) / 256, 256, 0, stream>>>(W, Un, Y, Wb);
    k_cast_x<<<(MROWS * DIN / 8) / 256, 256, 0, stream>>>(x, xb);
    k_gemm<<<(MROWS / 128) * (DOUT / 128), 256, 0, stream>>>(xb, Wb, bias, out);
}

// Round 2
// 562.760 us; speedup vs baseline: 1.3502x; 1.3007x over previous
//
#include <hip/hip_runtime.h>
#include <stdint.h>

#define DIN 4096
#define DOUT 4096
#define RNK 8
#define MROWS 8192   // B*S = 4*2048

typedef unsigned short u16;
typedef __attribute__((ext_vector_type(8))) short short8;
typedef __attribute__((ext_vector_type(8))) unsigned short u16x8;
typedef __attribute__((ext_vector_type(4))) float f32x4;

// ---------- helpers ----------
__device__ __forceinline__ u16 f2bf(float f) {
    union { float f; uint32_t u; } v; v.f = f;
    uint32_t u = v.u;
    uint32_t r = (u + 0x7fffu + ((u >> 16) & 1u)) >> 16;   // RNE
    return (u16)r;
}

__device__ __forceinline__ void gl_lds16(const u16* g, u16* lds) {
    // direct global->LDS DMA, 16B per lane; LDS dest = wave-uniform base + lane*16
    __builtin_amdgcn_global_load_lds((const __attribute__((address_space(1))) unsigned int*)g,
                                     (__attribute__((address_space(3))) unsigned int*)lds,
                                     16, 0, 0);
}

// ---------- K1: normalize columns of hra_u -> Un[i][d] ----------
__global__ __launch_bounds__(256) void k_normalize_u(const float* __restrict__ hra_u,
                                                     float* __restrict__ Un) {
    const int i = blockIdx.x;        // column 0..7
    const int t = threadIdx.x;
    float ss = 0.f;
    for (int d = t; d < DIN; d += 256) {
        float v = hra_u[d * RNK + i];
        ss += v * v;
    }
    for (int off = 32; off; off >>= 1) ss += __shfl_down(ss, off, 64);
    __shared__ float red[4];
    if ((t & 63) == 0) red[t >> 6] = ss;
    __syncthreads();
    float inv = rsqrtf(red[0] + red[1] + red[2] + red[3]);
    for (int d = t; d < DIN; d += 256)
        Un[i * DIN + d] = hra_u[d * RNK + i] * inv;
}

// ---------- K2: Gram matrix G[i][j] = Un[i] . Un[j] ----------
__global__ __launch_bounds__(256) void k_gram(const float* __restrict__ Un,
                                              float* __restrict__ G) {
    const int t = threadIdx.x;
    float acc[RNK][RNK] = {};
    for (int d = t; d < DIN; d += 256) {
        float u[RNK];
        #pragma unroll
        for (int i = 0; i < RNK; i++) u[i] = Un[i * DIN + d];
        #pragma unroll
        for (int i = 0; i < RNK; i++)
            #pragma unroll
            for (int j = 0; j < RNK; j++)
                acc[i][j] += u[i] * u[j];
    }
    #pragma unroll
    for (int i = 0; i < RNK; i++)
        #pragma unroll
        for (int j = 0; j < RNK; j++)
            for (int off = 32; off; off >>= 1)
                acc[i][j] += __shfl_down(acc[i][j], off, 64);
    __shared__ float red[4][64];
    if ((t & 63) == 0) {
        #pragma unroll
        for (int i = 0; i < RNK; i++)
            #pragma unroll
            for (int j = 0; j < RNK; j++)
                red[t >> 6][i * RNK + j] = acc[i][j];
    }
    __syncthreads();
    if (t < 64) G[t] = red[0][t] + red[1][t] + red[2][t] + red[3][t];
}

// ---------- K3 (fused): per row o: dots v_i = W[o,:].Un_i  -> triangular solve y ->
//            W'[o][d] = W[o][d] - sum_i y_i Un[i][d], cast bf16. W read ONCE from HBM. ----------
__global__ __launch_bounds__(256) void k_wy_build(const float* __restrict__ W,
                                                  const float* __restrict__ Un,
                                                  const float* __restrict__ G,
                                                  u16* __restrict__ Wb) {
    const int o = blockIdx.x;
    const int t = threadIdx.x;
    const float* wrow = W + (size_t)o * DIN;

    float4 wv[4];
    float acc[RNK] = {};
    #pragma unroll
    for (int j = 0; j < 4; j++) {
        const int c = t + j * 256;              // float4 chunk id
        wv[j] = *(const float4*)(wrow + c * 4);
        #pragma unroll
        for (int i = 0; i < RNK; i++) {
            float4 uv = *(const float4*)(Un + i * DIN + c * 4);
            acc[i] += wv[j].x * uv.x + wv[j].y * uv.y + wv[j].z * uv.z + wv[j].w * uv.w;
        }
    }
    #pragma unroll
    for (int i = 0; i < RNK; i++)
        for (int off = 32; off; off >>= 1)
            acc[i] += __shfl_down(acc[i], off, 64);
    __shared__ float red[4][RNK];
    __shared__ float ysh[RNK];
    if ((t & 63) == 0) {
        #pragma unroll
        for (int i = 0; i < RNK; i++) red[t >> 6][i] = acc[i];
    }
    __syncthreads();
    if (t == 0) {
        float y[RNK];
        #pragma unroll
        for (int i = 0; i < RNK; i++) {
            float s = red[0][i] + red[1][i] + red[2][i] + red[3][i];
            for (int j = 0; j < i; j++) s -= y[j] * G[j * RNK + i];
            y[i] = 2.f * s;
            ysh[i] = y[i];
        }
    }
    __syncthreads();
    float y[RNK];
    #pragma unroll
    for (int i = 0; i < RNK; i++) y[i] = ysh[i];

    #pragma unroll
    for (int j = 0; j < 4; j++) {
        const int c = t + j * 256;
        float4 r = wv[j];
        #pragma unroll
        for (int i = 0; i < RNK; i++) {
            float4 uv = *(const float4*)(Un + i * DIN + c * 4);   // L2-hot re-read
            r.x -= y[i] * uv.x; r.y -= y[i] * uv.y;
            r.z -= y[i] * uv.z; r.w -= y[i] * uv.w;
        }
        ushort4 ov;
        ov.x = f2bf(r.x); ov.y = f2bf(r.y); ov.z = f2bf(r.z); ov.w = f2bf(r.w);
        *(ushort4*)(Wb + (size_t)o * DIN + c * 4) = ov;
    }
}

// ---------- K4: cast x (fp32) -> bf16, grid-stride ----------
__global__ __launch_bounds__(256) void k_cast_x(const float* __restrict__ x,
                                                u16* __restrict__ xb) {
    const size_t total = (size_t)MROWS * DIN / 8;
    for (size_t idx = (size_t)blockIdx.x * 256 + threadIdx.x; idx < total;
         idx += (size_t)2048 * 256) {
        float4 a = *(const float4*)(x + idx * 8);
        float4 b = *(const float4*)(x + idx * 8 + 4);
        u16x8 o;
        o[0] = f2bf(a.x); o[1] = f2bf(a.y); o[2] = f2bf(a.z); o[3] = f2bf(a.w);
        o[4] = f2bf(b.x); o[5] = f2bf(b.y); o[6] = f2bf(b.z); o[7] = f2bf(b.w);
        *(u16x8*)(xb + idx * 8) = o;
    }
}

// ---------- K5: main GEMM  C[M,N] = A[M,K] @ B[N,K]^T + bias ----------
// 256x256 tile, 512 threads = 8 waves (2M x 4N), per-wave 128x64 output (acc[8][4]).
// BK=32, 4-deep LDS ring (4 x (16KB A + 16KB B) = 128 KiB). Per K-tile: 2 phases,
// each {ds_read subtile | issue 2 global_load_lds for tile t+3 | barrier |
// lgkmcnt(0) | setprio(1) | 16 MFMA | setprio(0) | barrier}; ONE counted
// s_waitcnt vmcnt(8) per tile (never 0): FIFO semantics guarantee tile t+1's
// stages (issued >=8 ops ago) are complete while t+2/t+3 stay in flight.
//
// LDS swizzle (2-row segments of 128B = 8 x 16B slots): slot p of segment s holds
// logical chunk lc = p ^ (s&7), lc = (row parity)*4 + kchunk. gl_lds writes
// linearly, so the INVERSE swizzle is applied to the per-lane global source
// (rule 21); ds_read applies the same XOR. Bank check: a quad-group's 16 lanes
// hit all 8 bank-quads twice -> 2-way = free.
__global__ __launch_bounds__(512, 2) void k_gemm(const u16* __restrict__ A,   // xb [M][K]
                                                 const u16* __restrict__ B,   // Wb [N][K]
                                                 const float* __restrict__ bias,
                                                 float* __restrict__ C) {
    __shared__ u16 sm[65536];   // 128 KiB: [buf 0..3][A:8192 | B:8192] u16

    const int t = threadIdx.x;
    const int w = t >> 6, l = t & 63;
    const int bm = blockIdx.x & 31;   // M/256 = 32  (linear bid: no XCD swizzle — L3-fit)
    const int bn = blockIdx.x >> 5;   // N/256 = 16
    const int wm = w >> 2, wn = w & 3;   // 2 x 4 wave grid

    const int quad = l >> 4, lane16 = l & 15;

    // ---- staging source (inverse-swizzled global address), per lane ----
    const int lc   = (l & 7) ^ (l >> 3);   // logical chunk within this lane's 2-row segment
    const int prow = lc >> 2;              // row parity
    const int kch  = lc & 3;               // k-chunk (8 bf16 = 16B)
    const int rA0  = (2 * w) * 16 + 2 * (l >> 3) + prow;   // issue-0 row within tile
    const u16* agp0 = A + (size_t)(bm * 256 + rA0) * DIN + kch * 8;
    const u16* agp1 = agp0 + (size_t)16 * DIN;             // issue-1: +16 rows
    const u16* bgp0 = B + (size_t)(bn * 256 + rA0) * DIN + kch * 8;
    const u16* bgp1 = bgp0 + (size_t)16 * DIN;
    const int ldso0 = (2 * w) * 512;       // u16 offset of this wave's issue-0 segment group
    const int ldso1 = (2 * w + 1) * 512;

    // ---- ds_read addressing (swizzled) ----
    // A frag row r = wm*128 + half*64 + mt*16 + lane16, chunk quad:
    //   addr_u16 = (r>>1)*64 + (((r&1)*4+quad) ^ ((r>>1)&7))*8 ; (r>>1)&7 == (lane16>>1)&7
    const int pA    = (((lane16 & 1) * 4 + quad) ^ ((lane16 >> 1) & 7)) * 8;
    const int a_off = (wm * 64 + (lane16 >> 1)) * 64 + pA;   // + (half*32 + mt*8)*64
    const int b_off = (wn * 32 + (lane16 >> 1)) * 64 + pA;   // + nt*8*64

    f32x4 acc[8][4] = {};

    const int NT = DIN / 32;   // 128 K-tiles

    // ---- prologue: stage tiles 0,1,2 into bufs 0,1,2 ----
    #pragma unroll
    for (int tt = 0; tt < 3; tt++) {
        u16* Asw = sm + tt * 16384;
        u16* Bsw = Asw + 8192;
        const int kc = tt * 32;
        gl_lds16(agp0 + kc, Asw + ldso0);
        gl_lds16(agp1 + kc, Asw + ldso1);
        gl_lds16(bgp0 + kc, Bsw + ldso0);
        gl_lds16(bgp1 + kc, Bsw + ldso1);
    }
    asm volatile("s_waitcnt vmcnt(8)" ::: "memory");   // tile 0 complete; 1,2 in flight
    __builtin_amdgcn_s_barrier();

    for (int kt = 0; kt < NT; kt++) {
        const u16* Asb = sm + (kt & 3) * 16384;
        const u16* Bsb = Asb + 8192;
        const bool pf = (kt + 3) < NT;
        u16* As3 = sm + ((kt + 3) & 3) * 16384;   // buf[(kt-1)&3]: readers done last tile
        u16* Bs3 = As3 + 8192;
        const int kc3 = (kt + 3) * 32;

        short8 a0[4], bfr[4];
        // ---------- phase 0: quadrant half=0 ----------
        #pragma unroll
        for (int mt = 0; mt < 4; mt++)
            a0[mt] = *(const short8*)&Asb[a_off + (mt * 8) * 64];
        #pragma unroll
        for (int nt = 0; nt < 4; nt++)
            bfr[nt] = *(const short8*)&Bsb[b_off + (nt * 8) * 64];
        if (pf) {
            gl_lds16(agp0 + kc3, As3 + ldso0);
            gl_lds16(agp1 + kc3, As3 + ldso1);
        }
        __builtin_amdgcn_s_barrier();
        asm volatile("s_waitcnt lgkmcnt(0)" ::: "memory");
        __builtin_amdgcn_s_setprio(1);
        #pragma unroll
        for (int mt = 0; mt < 4; mt++)
            #pragma unroll
            for (int nt = 0; nt < 4; nt++)
                acc[mt][nt] = __builtin_amdgcn_mfma_f32_16x16x32_bf16(
                    a0[mt], bfr[nt], acc[mt][nt], 0, 0, 0);
        __builtin_amdgcn_s_setprio(0);
        __builtin_amdgcn_s_barrier();

        // ---------- phase 1: quadrant half=1 (B frags reused from registers) ----------
        short8 a1[4];
        #pragma unroll
        for (int mt = 0; mt < 4; mt++)
            a1[mt] = *(const short8*)&Asb[a_off + (32 + mt * 8) * 64];
        if (pf) {
            gl_lds16(bgp0 + kc3, Bs3 + ldso0);
            gl_lds16(bgp1 + kc3, Bs3 + ldso1);
        }
        __builtin_amdgcn_s_barrier();
        asm volatile("s_waitcnt lgkmcnt(0)" ::: "memory");
        __builtin_amdgcn_s_setprio(1);
        #pragma unroll
        for (int mt = 0; mt < 4; mt++)
            #pragma unroll
            for (int nt = 0; nt < 4; nt++)
                acc[4 + mt][nt] = __builtin_amdgcn_mfma_f32_16x16x32_bf16(
                    a1[mt], bfr[nt], acc[4 + mt][nt], 0, 0, 0);
        __builtin_amdgcn_s_setprio(0);
        // counted wait: completes everything except the newest 8 issues (tiles kt+2, kt+3)
        // => tile kt+1 (issued during kt-2) is guaranteed landed before anyone reads it.
        asm volatile("s_waitcnt vmcnt(8)" ::: "memory");
        __builtin_amdgcn_s_barrier();
    }

    // ---- epilogue: D layout col=lane&15, row=quad*4+reg ----
    const int col0 = bn * 256 + wn * 64 + lane16;
    const int row00 = bm * 256 + wm * 128 + quad * 4;
    float bv[4];
    #pragma unroll
    for (int nt = 0; nt < 4; nt++) bv[nt] = bias[col0 + nt * 16];
    #pragma unroll
    for (int half = 0; half < 2; half++) {
        #pragma unroll
        for (int mt = 0; mt < 4; mt++) {
            const int row0 = row00 + half * 64 + mt * 16;
            #pragma unroll
            for (int nt = 0; nt < 4; nt++) {
                #pragma unroll
                for (int rr = 0; rr < 4; rr++) {
                    C[(size_t)(row0 + rr) * DOUT + col0 + nt * 16] =
                        acc[half * 4 + mt][nt][rr] + bv[nt];
                }
            }
        }
    }
}

extern "C" void kernel_launch(void* const* d_in, const int* in_sizes, int n_in,
                              void* d_out, int out_size, void* d_ws, size_t ws_size,
                              hipStream_t stream) {
    const float* x     = (const float*)d_in[0];   // [4,2048,4096]
    const float* hra_u = (const float*)d_in[1];   // [4096,8]
    const float* W     = (const float*)d_in[2];   // [4096,4096]
    const float* bias  = (const float*)d_in[3];   // [4096]
    float* out = (float*)d_out;

    char* ws = (char*)d_ws;
    float* Un = (float*)(ws);                         // 8*4096*4   = 131072 B
    float* G  = (float*)(ws + 131072);                // 64*4       = 256 B
    u16*   Wb = (u16*)(ws + 524288);                  // 4096*4096*2 = 33554432 B
    u16*   xb = (u16*)(ws + 524288 + 33554432);       // 8192*4096*2 = 67108864 B

    k_normalize_u<<<RNK, 256, 0, stream>>>(hra_u, Un);
    k_gram<<<1, 256, 0, stream>>>(Un, G);
    k_wy_build<<<DOUT, 256, 0, stream>>>(W, Un, G, Wb);
    k_cast_x<<<2048, 256, 0, stream>>>(x, xb);
    k_gemm<<<(MROWS / 256) * (DOUT / 256), 512, 0, stream>>>(xb, Wb, bias, out);
}